// Round 2
// 616.898 us; speedup vs baseline: 1.0043x; 1.0043x over previous
//
#include <hip/hip_runtime.h>
#include <hip/hip_bf16.h>
#include <stdint.h>

#define D_IN   2048
#define D_SAE  32768
#define K_NNZ  64

typedef float    vfloat4 __attribute__((ext_vector_type(4)));  // native vecs for
typedef uint32_t vuint4  __attribute__((ext_vector_type(4)));  // nontemporal builtins
typedef int      vint4   __attribute__((ext_vector_type(4)));

static __device__ __forceinline__ uint16_t bf16_bits(float x) {
  __hip_bfloat16 h = __float2bfloat16(x);
  return *reinterpret_cast<uint16_t*>(&h);
}

static __device__ __forceinline__ uint32_t pack2_bf16(float lo, float hi) {
  return (uint32_t)bf16_bits(lo) | ((uint32_t)bf16_bits(hi) << 16);
}

// ---------------------------------------------------------------------------
// Dedup precompute v2: scatter .set = last-write-wins. v_clean[r][k] = 0 if
// any k' > k shares idx. Also emits uint16 indices (D_SAE=32768 fits u16) so
// decode streams 3MB instead of 4MB per slice-pass. One wave per row.
// ---------------------------------------------------------------------------
__global__ __launch_bounds__(64) void dedup_values_v2(
    const int* __restrict__ indices, const float* __restrict__ values,
    float* __restrict__ v_clean, uint16_t* __restrict__ idx16) {
  __shared__ int si[K_NNZ];
  const int r = blockIdx.x;
  const int k = threadIdx.x;
  const int my = indices[(size_t)r * K_NNZ + k];
  si[k] = my;
  __syncthreads();
  float v = values[(size_t)r * K_NNZ + k];
  for (int k2 = k + 1; k2 < K_NNZ; ++k2) {
    if (si[k2] == my) { v = 0.0f; break; }
  }
  v_clean[(size_t)r * K_NNZ + k] = v;
  if (idx16) idx16[(size_t)r * K_NNZ + k] = (uint16_t)my;
}

// ---------------------------------------------------------------------------
// Transpose v3: W (2048 x 32768) fp32 -> WT (32768 x 2048) bf16.
// Tile 64(d) x 256(s); convert to bf16 IN PHASE A: LDS holds packed
// u32 = {bf16(d=2rp) | bf16(d=2rp+1)<<16} = 32KB (was 64KB fp32 -> 2 blk/CU;
// now 5 blk/CU). Phase B = 4 pure ds_read_b32 + uint4 store, no cvt VALU.
// Chunk swizzle c' = c ^ (((rp>>2)&7)<<2): phase-A b128 writes stay
// contiguous 16B (XOR bits >= bit2), phase-B reads <=2-way banked (free).
// ---------------------------------------------------------------------------
#define TP_D 64
#define TP_S 256

__global__ __launch_bounds__(256) void transpose_to_bf16_v3(
    const float* __restrict__ W, __hip_bfloat16* __restrict__ WT) {
  __shared__ uint32_t tile[32 * TP_S];  // [rp 0..31][c' 0..255], 32KB
  const int s0 = blockIdx.x * TP_S;
  const int d0 = blockIdx.y * TP_D;
  const int tid = threadIdx.x;
  const int w = tid >> 6, l = tid & 63;

  // Phase A: wave w loads row-pairs (w*16+2*ii, +1); one 1KB wave-load/row.
#pragma unroll
  for (int ii = 0; ii < 8; ++ii) {
    const int r = w * 16 + ii * 2;
    const int rp = r >> 1;  // w*8 + ii
    const vfloat4 va = __builtin_nontemporal_load(
        reinterpret_cast<const vfloat4*>(&W[(size_t)(d0 + r) * D_SAE + s0 + l * 4]));
    const vfloat4 vb = __builtin_nontemporal_load(
        reinterpret_cast<const vfloat4*>(&W[(size_t)(d0 + r + 1) * D_SAE + s0 + l * 4]));
    uint32_t u[4];
    u[0] = pack2_bf16(va.x, vb.x);
    u[1] = pack2_bf16(va.y, vb.y);
    u[2] = pack2_bf16(va.z, vb.z);
    u[3] = pack2_bf16(va.w, vb.w);
    const int E = ((rp >> 2) & 7) << 2;
    *reinterpret_cast<uint4*>(&tile[rp * TP_S + ((l * 4) ^ E)]) =
        *reinterpret_cast<uint4*>(u);
  }
  __syncthreads();

  // Phase B: wave w covers s_local [w*64, w*64+64); lane: a=d-chunk, sub=s.
  const int a = l & 7;
  const int sub = l >> 3;
#pragma unroll
  for (int i = 0; i < 8; ++i) {
    const int sl = w * 64 + i * 8 + sub;
    uint32_t u[4];
#pragma unroll
    for (int j = 0; j < 4; ++j) {
      const int rp = a * 4 + j;
      const int E = ((rp >> 2) & 7) << 2;  // = a<<2
      u[j] = tile[rp * TP_S + (sl ^ E)];
    }
    *reinterpret_cast<uint4*>(&WT[(size_t)(s0 + sl) * D_IN + d0 + a * 8]) =
        *reinterpret_cast<uint4*>(u);
  }
}

// ---------------------------------------------------------------------------
// Decode v4: L2-resident slices + row-chunk amortization, WT slice PROTECTED
// in L2: staging loads nontemporal (evict-first), idx stream u16 (3MB vs the
// exactly-4MB XCD L2 holding the WT slice). LDS 24KB -> 6 blk/CU. unroll 2
// on the row loop -> 16 gathers in flight per wave.
// ---------------------------------------------------------------------------
__global__ __launch_bounds__(256) void sae_decode_l2_v2(
    const uint16_t* __restrict__ idx16, const float* __restrict__ v_clean,
    const __hip_bfloat16* __restrict__ WT, const float* __restrict__ bias,
    float* __restrict__ out) {
  const int m = blockIdx.x & 7;
  const int rowchunk = blockIdx.x >> 3;
  const int slice = blockIdx.y * 8 + m;        // 0..31, XCD = slice%8
  const int col0 = slice * 64;
  const int r0 = rowchunk * 64;
  const int tid = threadIdx.x;
  const int w = tid >> 6, l = tid & 63;

  __shared__ __align__(16) uint16_t s_idx[64 * K_NNZ];  // 8KB
  __shared__ __align__(16) float    s_val[64 * K_NNZ];  // 16KB

  {  // stage 64 rows of (idx16, v_clean), nontemporal (don't evict WT slice)
    const vuint4*  gi = reinterpret_cast<const vuint4*>(&idx16[(size_t)r0 * K_NNZ]);
    const vfloat4* gv = reinterpret_cast<const vfloat4*>(&v_clean[(size_t)r0 * K_NNZ]);
#pragma unroll
    for (int i = 0; i < 2; ++i) {
      const int e = i * 256 + tid;
      reinterpret_cast<vuint4*>(s_idx)[e] = __builtin_nontemporal_load(&gi[e]);
    }
#pragma unroll
    for (int i = 0; i < 4; ++i) {
      const int e = i * 256 + tid;
      reinterpret_cast<vfloat4*>(s_val)[e] = __builtin_nontemporal_load(&gv[e]);
    }
  }
  __syncthreads();

  const int kg = l >> 3;                 // k-group 0..7
  const int c  = l & 7;                  // 16B chunk 0..7
  const __hip_bfloat16* wbase = WT + col0 + c * 8;

#pragma unroll 2
  for (int i = 0; i < 16; ++i) {
    const int r = w + 4 * i;
    float acc[8] = {0.f, 0.f, 0.f, 0.f, 0.f, 0.f, 0.f, 0.f};
#pragma unroll
    for (int step = 0; step < 8; ++step) {
      const int k = step * 8 + kg;
      const int idx = (int)s_idx[r * K_NNZ + k];  // broadcast across c
      const float v = s_val[r * K_NNZ + k];
      const uint4 wv = *reinterpret_cast<const uint4*>(&wbase[(size_t)idx * D_IN]);
#pragma unroll
      for (int j = 0; j < 4; ++j) {
        const uint32_t u = (&wv.x)[j];
        const float lo = __uint_as_float(u << 16);
        const float hi = __uint_as_float(u & 0xffff0000u);
        acc[2 * j + 0] = fmaf(v, lo, acc[2 * j + 0]);
        acc[2 * j + 1] = fmaf(v, hi, acc[2 * j + 1]);
      }
    }
#pragma unroll
    for (int j = 0; j < 8; ++j) {
      acc[j] += __shfl_xor(acc[j], 8, 64);
      acc[j] += __shfl_xor(acc[j], 16, 64);
      acc[j] += __shfl_xor(acc[j], 32, 64);
    }
    if (kg == 0) {
      const int dbase = col0 + c * 8;
      const float4 b0 = *reinterpret_cast<const float4*>(&bias[dbase]);
      const float4 b1 = *reinterpret_cast<const float4*>(&bias[dbase + 4]);
      vfloat4 o0 = {acc[0] + b0.x, acc[1] + b0.y, acc[2] + b0.z, acc[3] + b0.w};
      vfloat4 o1 = {acc[4] + b1.x, acc[5] + b1.y, acc[6] + b1.z, acc[7] + b1.w};
      vfloat4* o = reinterpret_cast<vfloat4*>(&out[(size_t)(r0 + r) * D_IN + dbase]);
      __builtin_nontemporal_store(o0, &o[0]);
      __builtin_nontemporal_store(o1, &o[1]);
    }
  }
}

// ---------------------------------------------------------------------------
// Fallback (ws fits WT+v_clean only): prior-round l2 decode, nt staging.
// ---------------------------------------------------------------------------
__global__ __launch_bounds__(256) void sae_decode_l2(
    const int* __restrict__ indices, const float* __restrict__ v_clean,
    const __hip_bfloat16* __restrict__ WT, const float* __restrict__ bias,
    float* __restrict__ out) {
  const int m = blockIdx.x & 7;
  const int rowchunk = blockIdx.x >> 3;
  const int slice = blockIdx.y * 8 + m;
  const int col0 = slice * 64;
  const int r0 = rowchunk * 64;
  const int tid = threadIdx.x;
  const int w = tid >> 6, l = tid & 63;

  __shared__ __align__(16) int   s_idx[64 * K_NNZ];
  __shared__ __align__(16) float s_val[64 * K_NNZ];

  {
    const vint4*   gi = reinterpret_cast<const vint4*>(&indices[(size_t)r0 * K_NNZ]);
    const vfloat4* gv = reinterpret_cast<const vfloat4*>(&v_clean[(size_t)r0 * K_NNZ]);
#pragma unroll
    for (int i = 0; i < 4; ++i) {
      const int e = i * 256 + tid;
      reinterpret_cast<vint4*>(s_idx)[e] = __builtin_nontemporal_load(&gi[e]);
      reinterpret_cast<vfloat4*>(s_val)[e] = __builtin_nontemporal_load(&gv[e]);
    }
  }
  __syncthreads();

  const int kg = l >> 3;
  const int c  = l & 7;
  const __hip_bfloat16* wbase = WT + col0 + c * 8;

  for (int i = 0; i < 16; ++i) {
    const int r = w + 4 * i;
    float acc[8] = {0.f, 0.f, 0.f, 0.f, 0.f, 0.f, 0.f, 0.f};
#pragma unroll
    for (int step = 0; step < 8; ++step) {
      const int k = step * 8 + kg;
      const int idx = s_idx[r * K_NNZ + k];
      const float v = s_val[r * K_NNZ + k];
      const uint4 wv = *reinterpret_cast<const uint4*>(&wbase[(size_t)idx * D_IN]);
#pragma unroll
      for (int j = 0; j < 4; ++j) {
        const uint32_t u = (&wv.x)[j];
        const float lo = __uint_as_float(u << 16);
        const float hi = __uint_as_float(u & 0xffff0000u);
        acc[2 * j + 0] = fmaf(v, lo, acc[2 * j + 0]);
        acc[2 * j + 1] = fmaf(v, hi, acc[2 * j + 1]);
      }
    }
#pragma unroll
    for (int j = 0; j < 8; ++j) {
      acc[j] += __shfl_xor(acc[j], 8, 64);
      acc[j] += __shfl_xor(acc[j], 16, 64);
      acc[j] += __shfl_xor(acc[j], 32, 64);
    }
    if (kg == 0) {
      const int dbase = col0 + c * 8;
      const float4 b0 = *reinterpret_cast<const float4*>(&bias[dbase]);
      const float4 b1 = *reinterpret_cast<const float4*>(&bias[dbase + 4]);
      vfloat4 o0 = {acc[0] + b0.x, acc[1] + b0.y, acc[2] + b0.z, acc[3] + b0.w};
      vfloat4 o1 = {acc[4] + b1.x, acc[5] + b1.y, acc[6] + b1.z, acc[7] + b1.w};
      vfloat4* o = reinterpret_cast<vfloat4*>(&out[(size_t)(r0 + r) * D_IN + dbase]);
      __builtin_nontemporal_store(o0, &o[0]);
      __builtin_nontemporal_store(o1, &o[1]);
    }
  }
}

// ---------------------------------------------------------------------------
// Fallback A (ws fits WT only): R1's proven decode (in-kernel dedup).
// ---------------------------------------------------------------------------
__global__ __launch_bounds__(256) void sae_decode_r1(
    const int* __restrict__ indices, const float* __restrict__ values,
    const __hip_bfloat16* __restrict__ WT, const float* __restrict__ bias,
    float* __restrict__ out) {
  const int row = blockIdx.x;
  const int tid = threadIdx.x;

  __shared__ int   s_idx[K_NNZ];
  __shared__ float s_val[K_NNZ];
  if (tid < K_NNZ) {
    s_idx[tid] = indices[(size_t)row * K_NNZ + tid];
    s_val[tid] = values[(size_t)row * K_NNZ + tid];
  }
  __syncthreads();
  if (tid < K_NNZ) {
    const int my = s_idx[tid];
    for (int k2 = tid + 1; k2 < K_NNZ; ++k2) {
      if (s_idx[k2] == my) { s_val[tid] = 0.0f; break; }
    }
  }
  __syncthreads();

  const int d0 = tid * 8;
  float acc[8];
  {
    const float4 b0 = *reinterpret_cast<const float4*>(&bias[d0]);
    const float4 b1 = *reinterpret_cast<const float4*>(&bias[d0 + 4]);
    acc[0] = b0.x; acc[1] = b0.y; acc[2] = b0.z; acc[3] = b0.w;
    acc[4] = b1.x; acc[5] = b1.y; acc[6] = b1.z; acc[7] = b1.w;
  }
#pragma unroll 4
  for (int k = 0; k < K_NNZ; ++k) {
    const float v = s_val[k];
    const int idx = s_idx[k];
    const uint4 wv = *reinterpret_cast<const uint4*>(
        &WT[(size_t)idx * D_IN + d0]);
#pragma unroll
    for (int j = 0; j < 4; ++j) {
      const uint32_t u = (&wv.x)[j];
      const float lo = __uint_as_float(u << 16);
      const float hi = __uint_as_float(u & 0xffff0000u);
      acc[2 * j + 0] = fmaf(v, lo, acc[2 * j + 0]);
      acc[2 * j + 1] = fmaf(v, hi, acc[2 * j + 1]);
    }
  }
  float4* o = reinterpret_cast<float4*>(&out[(size_t)row * D_IN + d0]);
  o[0] = make_float4(acc[0], acc[1], acc[2], acc[3]);
  o[1] = make_float4(acc[4], acc[5], acc[6], acc[7]);
}

// ---------------------------------------------------------------------------
// Fallback B (tiny ws): direct fp32 gather. Insurance only.
// ---------------------------------------------------------------------------
__global__ __launch_bounds__(256) void sae_decode_direct(
    const int* __restrict__ indices, const float* __restrict__ values,
    const float* __restrict__ W, const float* __restrict__ bias,
    float* __restrict__ out) {
  const int row = blockIdx.x;
  const int tid = threadIdx.x;
  __shared__ int   s_idx[K_NNZ];
  __shared__ float s_val[K_NNZ];
  if (tid < K_NNZ) {
    s_idx[tid] = indices[(size_t)row * K_NNZ + tid];
    s_val[tid] = values[(size_t)row * K_NNZ + tid];
  }
  __syncthreads();
  if (tid < K_NNZ) {
    const int my = s_idx[tid];
    for (int k2 = tid + 1; k2 < K_NNZ; ++k2) {
      if (s_idx[k2] == my) { s_val[tid] = 0.0f; break; }
    }
  }
  __syncthreads();
  const int d0 = tid * 8;
  float acc[8];
#pragma unroll
  for (int j = 0; j < 8; ++j) acc[j] = bias[d0 + j];
  for (int k = 0; k < K_NNZ; ++k) {
    const float v = s_val[k];
    const int idx = s_idx[k];
#pragma unroll
    for (int j = 0; j < 8; ++j) {
      acc[j] = fmaf(v, W[(size_t)(d0 + j) * D_SAE + idx], acc[j]);
    }
  }
  float4* o = reinterpret_cast<float4*>(&out[(size_t)row * D_IN + d0]);
  o[0] = make_float4(acc[0], acc[1], acc[2], acc[3]);
  o[1] = make_float4(acc[4], acc[5], acc[6], acc[7]);
}

extern "C" void kernel_launch(void* const* d_in, const int* in_sizes, int n_in,
                              void* d_out, int out_size, void* d_ws, size_t ws_size,
                              hipStream_t stream) {
  const int*   indices = (const int*)d_in[0];
  const float* values  = (const float*)d_in[1];
  const float* W       = (const float*)d_in[2];
  const float* bias    = (const float*)d_in[3];
  float* out = (float*)d_out;

  const int n_rows = in_sizes[0] / K_NNZ;  // 8192
  const size_t wt_bytes = (size_t)D_SAE * D_IN * sizeof(__hip_bfloat16);  // 128MB
  const size_t vc_bytes = (size_t)n_rows * K_NNZ * sizeof(float);         // 2MB
  const size_t ix_bytes = (size_t)n_rows * K_NNZ * sizeof(uint16_t);      // 1MB

  if (ws_size >= wt_bytes + vc_bytes + ix_bytes && (n_rows % 64) == 0) {
    __hip_bfloat16* WT = (__hip_bfloat16*)d_ws;
    float* v_clean = (float*)((char*)d_ws + wt_bytes);
    uint16_t* idx16 = (uint16_t*)((char*)d_ws + wt_bytes + vc_bytes);
    transpose_to_bf16_v3<<<dim3(D_SAE / TP_S, D_IN / TP_D), 256, 0, stream>>>(W, WT);
    dedup_values_v2<<<n_rows, 64, 0, stream>>>(indices, values, v_clean, idx16);
    dim3 g2(8 * (n_rows / 64), 4);  // x: rowchunk*8+xcd, y: phase
    sae_decode_l2_v2<<<g2, 256, 0, stream>>>(idx16, v_clean, WT, bias, out);
  } else if (ws_size >= wt_bytes + vc_bytes && (n_rows % 64) == 0) {
    __hip_bfloat16* WT = (__hip_bfloat16*)d_ws;
    float* v_clean = (float*)((char*)d_ws + wt_bytes);
    transpose_to_bf16_v3<<<dim3(D_SAE / TP_S, D_IN / TP_D), 256, 0, stream>>>(W, WT);
    dedup_values_v2<<<n_rows, 64, 0, stream>>>(indices, values, v_clean,
                                               (uint16_t*)nullptr);
    dim3 g2(8 * (n_rows / 64), 4);
    sae_decode_l2<<<g2, 256, 0, stream>>>(indices, v_clean, WT, bias, out);
  } else if (ws_size >= wt_bytes) {
    __hip_bfloat16* WT = (__hip_bfloat16*)d_ws;
    transpose_to_bf16_v3<<<dim3(D_SAE / TP_S, D_IN / TP_D), 256, 0, stream>>>(W, WT);
    sae_decode_r1<<<n_rows, 256, 0, stream>>>(indices, values, WT, bias, out);
  } else {
    sae_decode_direct<<<n_rows, 256, 0, stream>>>(indices, values, W, bias, out);
  }
}

// Round 3
// 614.778 us; speedup vs baseline: 1.0078x; 1.0034x over previous
//
#include <hip/hip_runtime.h>
#include <hip/hip_bf16.h>
#include <stdint.h>

#define D_IN   2048
#define D_SAE  32768
#define K_NNZ  64

typedef float    vfloat4 __attribute__((ext_vector_type(4)));  // native vecs for
typedef uint32_t vuint4  __attribute__((ext_vector_type(4)));  // nontemporal builtins
typedef int      vint4   __attribute__((ext_vector_type(4)));

static __device__ __forceinline__ uint16_t bf16_bits(float x) {
  __hip_bfloat16 h = __float2bfloat16(x);
  return *reinterpret_cast<uint16_t*>(&h);
}

static __device__ __forceinline__ uint32_t pack2_bf16(float lo, float hi) {
  return (uint32_t)bf16_bits(lo) | ((uint32_t)bf16_bits(hi) << 16);
}

// ---------------------------------------------------------------------------
// Dedup precompute v2: scatter .set = last-write-wins. v_clean[r][k] = 0 if
// any k' > k shares idx. Also emits uint16 indices (D_SAE=32768 fits u16).
// One wave per row.
// ---------------------------------------------------------------------------
__global__ __launch_bounds__(64) void dedup_values_v2(
    const int* __restrict__ indices, const float* __restrict__ values,
    float* __restrict__ v_clean, uint16_t* __restrict__ idx16) {
  __shared__ int si[K_NNZ];
  const int r = blockIdx.x;
  const int k = threadIdx.x;
  const int my = indices[(size_t)r * K_NNZ + k];
  si[k] = my;
  __syncthreads();
  float v = values[(size_t)r * K_NNZ + k];
  for (int k2 = k + 1; k2 < K_NNZ; ++k2) {
    if (si[k2] == my) { v = 0.0f; break; }
  }
  v_clean[(size_t)r * K_NNZ + k] = v;
  if (idx16) idx16[(size_t)r * K_NNZ + k] = (uint16_t)my;
}

// ---------------------------------------------------------------------------
// Transpose v4: W (2048 x 32768) fp32 -> WT (32768 x 2048) bf16.
// Tile 32(d) x 256(s), packed-bf16 LDS = 16 rp x 260-word pitch = 16.3KB
// -> 8 blocks/CU = 100% occupancy (v3's 32KB tile capped at 5 blk/CU, 62%).
// Pitch 260 (=4 mod 32 banks): phase-B b32 reads are 2-way banked = free
// (m136), phase-A b128 writes canonical stride-16B = conflict-free. No XOR
// swizzle needed. nt loads on W (streamed once, keep L2 for stores).
// ---------------------------------------------------------------------------
#define TP_D 32
#define TP_S 256
#define TP_P 260

__global__ __launch_bounds__(256) void transpose_to_bf16_v4(
    const float* __restrict__ W, __hip_bfloat16* __restrict__ WT) {
  __shared__ uint32_t tile[16 * TP_P];  // 16.3KB
  const int s0 = blockIdx.x * TP_S;
  const int d0 = blockIdx.y * TP_D;
  const int tid = threadIdx.x;
  const int w = tid >> 6, l = tid & 63;

  // Phase A: wave w loads rows w*8 .. w*8+7 (4 row-pairs); 1KB wave-load/row.
#pragma unroll
  for (int ii = 0; ii < 4; ++ii) {
    const int r = w * 8 + ii * 2;
    const int rp = (w << 2) + ii;  // r>>1, in [0,16)
    const vfloat4 va = __builtin_nontemporal_load(
        reinterpret_cast<const vfloat4*>(&W[(size_t)(d0 + r) * D_SAE + s0 + l * 4]));
    const vfloat4 vb = __builtin_nontemporal_load(
        reinterpret_cast<const vfloat4*>(&W[(size_t)(d0 + r + 1) * D_SAE + s0 + l * 4]));
    uint32_t u[4];
    u[0] = pack2_bf16(va.x, vb.x);
    u[1] = pack2_bf16(va.y, vb.y);
    u[2] = pack2_bf16(va.z, vb.z);
    u[3] = pack2_bf16(va.w, vb.w);
    *reinterpret_cast<uint4*>(&tile[rp * TP_P + l * 4]) =
        *reinterpret_cast<uint4*>(u);
  }
  __syncthreads();

  // Phase B: lane a=l&3 picks d-chunk of 8, sub=l>>2 picks s; wave w covers
  // s_local [w*64, w*64+64) in 4 iters of 16 s-rows.
  const int a = l & 3;
  const int sub = l >> 2;
#pragma unroll
  for (int i = 0; i < 4; ++i) {
    const int sl = w * 64 + i * 16 + sub;
    uint32_t u[4];
#pragma unroll
    for (int j = 0; j < 4; ++j) {
      const int rp = a * 4 + j;
      u[j] = tile[rp * TP_P + sl];
    }
    *reinterpret_cast<uint4*>(&WT[(size_t)(s0 + sl) * D_IN + d0 + a * 8]) =
        *reinterpret_cast<uint4*>(u);
  }
}

// ---------------------------------------------------------------------------
// Decode v5: slice loop INSIDE the block. Grid = 8 XCDs x 128 rowchunks =
// 1024 blocks; block (m, rc) stages idx/val for its 64 rows ONCE, then
// processes slices {m, m+8, m+16, m+24} sequentially. All 128 blocks of an
// XCD are co-resident (4 blk/CU needed, 6 fit at 24KB LDS), so the whole
// XCD sweeps one 4MB WT slice at a time -> slice stays L2-resident.
// (v4 failed: 190 resident blocks vs 128-block phases meant TWO slices
// always contended for one 4MB L2 -> WT re-fetched 4.5x, FETCH 680MB.)
// idx/val total read drops 96MB -> 3MB (staged once, not once per slice).
// ---------------------------------------------------------------------------
__global__ __launch_bounds__(256) void sae_decode_l2_v3(
    const uint16_t* __restrict__ idx16, const float* __restrict__ v_clean,
    const __hip_bfloat16* __restrict__ WT, const float* __restrict__ bias,
    float* __restrict__ out) {
  const int m = blockIdx.x & 7;            // XCD
  const int rowchunk = blockIdx.x >> 3;    // 0..n_rows/64-1
  const int r0 = rowchunk * 64;
  const int tid = threadIdx.x;
  const int w = tid >> 6, l = tid & 63;

  __shared__ __align__(16) uint16_t s_idx[64 * K_NNZ];  // 8KB
  __shared__ __align__(16) float    s_val[64 * K_NNZ];  // 16KB

  {  // stage 64 rows of (idx16, v_clean) once; nt (read-once stream)
    const vuint4*  gi = reinterpret_cast<const vuint4*>(&idx16[(size_t)r0 * K_NNZ]);
    const vfloat4* gv = reinterpret_cast<const vfloat4*>(&v_clean[(size_t)r0 * K_NNZ]);
#pragma unroll
    for (int i = 0; i < 2; ++i) {
      const int e = i * 256 + tid;
      reinterpret_cast<vuint4*>(s_idx)[e] = __builtin_nontemporal_load(&gi[e]);
    }
#pragma unroll
    for (int i = 0; i < 4; ++i) {
      const int e = i * 256 + tid;
      reinterpret_cast<vfloat4*>(s_val)[e] = __builtin_nontemporal_load(&gv[e]);
    }
  }
  __syncthreads();

  const int kg = l >> 3;                 // k-group 0..7
  const int c  = l & 7;                  // 16B chunk 0..7

  for (int s = 0; s < 4; ++s) {          // slices m, m+8, m+16, m+24
    const int col0 = (s * 8 + m) * 64;
    const __hip_bfloat16* wbase = WT + col0 + c * 8;

#pragma unroll 2
    for (int i = 0; i < 16; ++i) {
      const int r = w + 4 * i;
      float acc[8] = {0.f, 0.f, 0.f, 0.f, 0.f, 0.f, 0.f, 0.f};
#pragma unroll
      for (int step = 0; step < 8; ++step) {
        const int k = step * 8 + kg;
        const int idx = (int)s_idx[r * K_NNZ + k];  // broadcast across c
        const float v = s_val[r * K_NNZ + k];
        const uint4 wv = *reinterpret_cast<const uint4*>(&wbase[(size_t)idx * D_IN]);
#pragma unroll
        for (int j = 0; j < 4; ++j) {
          const uint32_t u = (&wv.x)[j];
          const float lo = __uint_as_float(u << 16);
          const float hi = __uint_as_float(u & 0xffff0000u);
          acc[2 * j + 0] = fmaf(v, lo, acc[2 * j + 0]);
          acc[2 * j + 1] = fmaf(v, hi, acc[2 * j + 1]);
        }
      }
#pragma unroll
      for (int j = 0; j < 8; ++j) {
        acc[j] += __shfl_xor(acc[j], 8, 64);
        acc[j] += __shfl_xor(acc[j], 16, 64);
        acc[j] += __shfl_xor(acc[j], 32, 64);
      }
      if (kg == 0) {
        const int dbase = col0 + c * 8;
        const float4 b0 = *reinterpret_cast<const float4*>(&bias[dbase]);
        const float4 b1 = *reinterpret_cast<const float4*>(&bias[dbase + 4]);
        vfloat4 o0 = {acc[0] + b0.x, acc[1] + b0.y, acc[2] + b0.z, acc[3] + b0.w};
        vfloat4 o1 = {acc[4] + b1.x, acc[5] + b1.y, acc[6] + b1.z, acc[7] + b1.w};
        vfloat4* o = reinterpret_cast<vfloat4*>(&out[(size_t)(r0 + r) * D_IN + dbase]);
        __builtin_nontemporal_store(o0, &o[0]);
        __builtin_nontemporal_store(o1, &o[1]);
      }
    }
  }
}

// ---------------------------------------------------------------------------
// Fallback (ws fits WT+v_clean only): int32-staging variant, same slice-loop
// structure.
// ---------------------------------------------------------------------------
__global__ __launch_bounds__(256) void sae_decode_l2(
    const int* __restrict__ indices, const float* __restrict__ v_clean,
    const __hip_bfloat16* __restrict__ WT, const float* __restrict__ bias,
    float* __restrict__ out) {
  const int m = blockIdx.x & 7;
  const int rowchunk = blockIdx.x >> 3;
  const int r0 = rowchunk * 64;
  const int tid = threadIdx.x;
  const int w = tid >> 6, l = tid & 63;

  __shared__ __align__(16) int   s_idx[64 * K_NNZ];
  __shared__ __align__(16) float s_val[64 * K_NNZ];

  {
    const vint4*   gi = reinterpret_cast<const vint4*>(&indices[(size_t)r0 * K_NNZ]);
    const vfloat4* gv = reinterpret_cast<const vfloat4*>(&v_clean[(size_t)r0 * K_NNZ]);
#pragma unroll
    for (int i = 0; i < 4; ++i) {
      const int e = i * 256 + tid;
      reinterpret_cast<vint4*>(s_idx)[e] = __builtin_nontemporal_load(&gi[e]);
      reinterpret_cast<vfloat4*>(s_val)[e] = __builtin_nontemporal_load(&gv[e]);
    }
  }
  __syncthreads();

  const int kg = l >> 3;
  const int c  = l & 7;

  for (int s = 0; s < 4; ++s) {
    const int col0 = (s * 8 + m) * 64;
    const __hip_bfloat16* wbase = WT + col0 + c * 8;

    for (int i = 0; i < 16; ++i) {
      const int r = w + 4 * i;
      float acc[8] = {0.f, 0.f, 0.f, 0.f, 0.f, 0.f, 0.f, 0.f};
#pragma unroll
      for (int step = 0; step < 8; ++step) {
        const int k = step * 8 + kg;
        const int idx = s_idx[r * K_NNZ + k];
        const float v = s_val[r * K_NNZ + k];
        const uint4 wv = *reinterpret_cast<const uint4*>(&wbase[(size_t)idx * D_IN]);
#pragma unroll
        for (int j = 0; j < 4; ++j) {
          const uint32_t u = (&wv.x)[j];
          const float lo = __uint_as_float(u << 16);
          const float hi = __uint_as_float(u & 0xffff0000u);
          acc[2 * j + 0] = fmaf(v, lo, acc[2 * j + 0]);
          acc[2 * j + 1] = fmaf(v, hi, acc[2 * j + 1]);
        }
      }
#pragma unroll
      for (int j = 0; j < 8; ++j) {
        acc[j] += __shfl_xor(acc[j], 8, 64);
        acc[j] += __shfl_xor(acc[j], 16, 64);
        acc[j] += __shfl_xor(acc[j], 32, 64);
      }
      if (kg == 0) {
        const int dbase = col0 + c * 8;
        const float4 b0 = *reinterpret_cast<const float4*>(&bias[dbase]);
        const float4 b1 = *reinterpret_cast<const float4*>(&bias[dbase + 4]);
        vfloat4 o0 = {acc[0] + b0.x, acc[1] + b0.y, acc[2] + b0.z, acc[3] + b0.w};
        vfloat4 o1 = {acc[4] + b1.x, acc[5] + b1.y, acc[6] + b1.z, acc[7] + b1.w};
        vfloat4* o = reinterpret_cast<vfloat4*>(&out[(size_t)(r0 + r) * D_IN + dbase]);
        __builtin_nontemporal_store(o0, &o[0]);
        __builtin_nontemporal_store(o1, &o[1]);
      }
    }
  }
}

// ---------------------------------------------------------------------------
// Fallback A (ws fits WT only): R1's proven decode (in-kernel dedup).
// ---------------------------------------------------------------------------
__global__ __launch_bounds__(256) void sae_decode_r1(
    const int* __restrict__ indices, const float* __restrict__ values,
    const __hip_bfloat16* __restrict__ WT, const float* __restrict__ bias,
    float* __restrict__ out) {
  const int row = blockIdx.x;
  const int tid = threadIdx.x;

  __shared__ int   s_idx[K_NNZ];
  __shared__ float s_val[K_NNZ];
  if (tid < K_NNZ) {
    s_idx[tid] = indices[(size_t)row * K_NNZ + tid];
    s_val[tid] = values[(size_t)row * K_NNZ + tid];
  }
  __syncthreads();
  if (tid < K_NNZ) {
    const int my = s_idx[tid];
    for (int k2 = tid + 1; k2 < K_NNZ; ++k2) {
      if (s_idx[k2] == my) { s_val[tid] = 0.0f; break; }
    }
  }
  __syncthreads();

  const int d0 = tid * 8;
  float acc[8];
  {
    const float4 b0 = *reinterpret_cast<const float4*>(&bias[d0]);
    const float4 b1 = *reinterpret_cast<const float4*>(&bias[d0 + 4]);
    acc[0] = b0.x; acc[1] = b0.y; acc[2] = b0.z; acc[3] = b0.w;
    acc[4] = b1.x; acc[5] = b1.y; acc[6] = b1.z; acc[7] = b1.w;
  }
#pragma unroll 4
  for (int k = 0; k < K_NNZ; ++k) {
    const float v = s_val[k];
    const int idx = s_idx[k];
    const uint4 wv = *reinterpret_cast<const uint4*>(
        &WT[(size_t)idx * D_IN + d0]);
#pragma unroll
    for (int j = 0; j < 4; ++j) {
      const uint32_t u = (&wv.x)[j];
      const float lo = __uint_as_float(u << 16);
      const float hi = __uint_as_float(u & 0xffff0000u);
      acc[2 * j + 0] = fmaf(v, lo, acc[2 * j + 0]);
      acc[2 * j + 1] = fmaf(v, hi, acc[2 * j + 1]);
    }
  }
  float4* o = reinterpret_cast<float4*>(&out[(size_t)row * D_IN + d0]);
  o[0] = make_float4(acc[0], acc[1], acc[2], acc[3]);
  o[1] = make_float4(acc[4], acc[5], acc[6], acc[7]);
}

// ---------------------------------------------------------------------------
// Fallback B (tiny ws): direct fp32 gather. Insurance only.
// ---------------------------------------------------------------------------
__global__ __launch_bounds__(256) void sae_decode_direct(
    const int* __restrict__ indices, const float* __restrict__ values,
    const float* __restrict__ W, const float* __restrict__ bias,
    float* __restrict__ out) {
  const int row = blockIdx.x;
  const int tid = threadIdx.x;
  __shared__ int   s_idx[K_NNZ];
  __shared__ float s_val[K_NNZ];
  if (tid < K_NNZ) {
    s_idx[tid] = indices[(size_t)row * K_NNZ + tid];
    s_val[tid] = values[(size_t)row * K_NNZ + tid];
  }
  __syncthreads();
  if (tid < K_NNZ) {
    const int my = s_idx[tid];
    for (int k2 = tid + 1; k2 < K_NNZ; ++k2) {
      if (s_idx[k2] == my) { s_val[tid] = 0.0f; break; }
    }
  }
  __syncthreads();
  const int d0 = tid * 8;
  float acc[8];
#pragma unroll
  for (int j = 0; j < 8; ++j) acc[j] = bias[d0 + j];
  for (int k = 0; k < K_NNZ; ++k) {
    const float v = s_val[k];
    const int idx = s_idx[k];
#pragma unroll
    for (int j = 0; j < 8; ++j) {
      acc[j] = fmaf(v, W[(size_t)(d0 + j) * D_SAE + idx], acc[j]);
    }
  }
  float4* o = reinterpret_cast<float4*>(&out[(size_t)row * D_IN + d0]);
  o[0] = make_float4(acc[0], acc[1], acc[2], acc[3]);
  o[1] = make_float4(acc[4], acc[5], acc[6], acc[7]);
}

extern "C" void kernel_launch(void* const* d_in, const int* in_sizes, int n_in,
                              void* d_out, int out_size, void* d_ws, size_t ws_size,
                              hipStream_t stream) {
  const int*   indices = (const int*)d_in[0];
  const float* values  = (const float*)d_in[1];
  const float* W       = (const float*)d_in[2];
  const float* bias    = (const float*)d_in[3];
  float* out = (float*)d_out;

  const int n_rows = in_sizes[0] / K_NNZ;  // 8192
  const size_t wt_bytes = (size_t)D_SAE * D_IN * sizeof(__hip_bfloat16);  // 128MB
  const size_t vc_bytes = (size_t)n_rows * K_NNZ * sizeof(float);         // 2MB
  const size_t ix_bytes = (size_t)n_rows * K_NNZ * sizeof(uint16_t);      // 1MB

  if (ws_size >= wt_bytes + vc_bytes + ix_bytes && (n_rows % 64) == 0) {
    __hip_bfloat16* WT = (__hip_bfloat16*)d_ws;
    float* v_clean = (float*)((char*)d_ws + wt_bytes);
    uint16_t* idx16 = (uint16_t*)((char*)d_ws + wt_bytes + vc_bytes);
    transpose_to_bf16_v4<<<dim3(D_SAE / TP_S, D_IN / TP_D), 256, 0, stream>>>(W, WT);
    dedup_values_v2<<<n_rows, 64, 0, stream>>>(indices, values, v_clean, idx16);
    sae_decode_l2_v3<<<8 * (n_rows / 64), 256, 0, stream>>>(idx16, v_clean, WT,
                                                            bias, out);
  } else if (ws_size >= wt_bytes + vc_bytes && (n_rows % 64) == 0) {
    __hip_bfloat16* WT = (__hip_bfloat16*)d_ws;
    float* v_clean = (float*)((char*)d_ws + wt_bytes);
    transpose_to_bf16_v4<<<dim3(D_SAE / TP_S, D_IN / TP_D), 256, 0, stream>>>(W, WT);
    dedup_values_v2<<<n_rows, 64, 0, stream>>>(indices, values, v_clean,
                                               (uint16_t*)nullptr);
    sae_decode_l2<<<8 * (n_rows / 64), 256, 0, stream>>>(indices, v_clean, WT,
                                                         bias, out);
  } else if (ws_size >= wt_bytes) {
    __hip_bfloat16* WT = (__hip_bfloat16*)d_ws;
    transpose_to_bf16_v4<<<dim3(D_SAE / TP_S, D_IN / TP_D), 256, 0, stream>>>(W, WT);
    sae_decode_r1<<<n_rows, 256, 0, stream>>>(indices, values, WT, bias, out);
  } else {
    sae_decode_direct<<<n_rows, 256, 0, stream>>>(indices, values, W, bias, out);
  }
}

// Round 4
// 506.238 us; speedup vs baseline: 1.2238x; 1.2144x over previous
//
#include <hip/hip_runtime.h>
#include <hip/hip_bf16.h>
#include <stdint.h>

#define D_IN   2048
#define D_SAE  32768
#define K_NNZ  64

typedef float    vfloat4 __attribute__((ext_vector_type(4)));  // native vecs for
typedef uint32_t vuint4  __attribute__((ext_vector_type(4)));  // nontemporal builtins
typedef int      vint4   __attribute__((ext_vector_type(4)));

static __device__ __forceinline__ uint16_t bf16_bits(float x) {
  __hip_bfloat16 h = __float2bfloat16(x);
  return *reinterpret_cast<uint16_t*>(&h);
}

static __device__ __forceinline__ uint32_t pack2_bf16(float lo, float hi) {
  return (uint32_t)bf16_bits(lo) | ((uint32_t)bf16_bits(hi) << 16);
}

// ---------------------------------------------------------------------------
// Dedup precompute v2: scatter .set = last-write-wins. v_clean[r][k] = 0 if
// any k' > k shares idx. Also emits uint16 indices (D_SAE=32768 fits u16).
// One wave per row.
// ---------------------------------------------------------------------------
__global__ __launch_bounds__(64) void dedup_values_v2(
    const int* __restrict__ indices, const float* __restrict__ values,
    float* __restrict__ v_clean, uint16_t* __restrict__ idx16) {
  __shared__ int si[K_NNZ];
  const int r = blockIdx.x;
  const int k = threadIdx.x;
  const int my = indices[(size_t)r * K_NNZ + k];
  si[k] = my;
  __syncthreads();
  float v = values[(size_t)r * K_NNZ + k];
  for (int k2 = k + 1; k2 < K_NNZ; ++k2) {
    if (si[k2] == my) { v = 0.0f; break; }
  }
  v_clean[(size_t)r * K_NNZ + k] = v;
  if (idx16) idx16[(size_t)r * K_NNZ + k] = (uint16_t)my;
}

// ---------------------------------------------------------------------------
// Transpose v5 (BLOCKED output): W (2048 x 32768) fp32 ->
// WT_b[32 slices][32768 s][64 d] bf16. A slice is a CONTIGUOUS 4MB region;
// gather of (idx, slice) in decode = one aligned 128B line at idx*128B.
// (v3/v4 row-major WT put a slice's lines at stride 4096B with fixed low
// bits -> L2 set index bits constant -> slice aliased into ~1/32 of the
// sets -> only ~128KB resident -> measured 4.5x WT refetch. Blocked layout
// gives uniform set coverage so the slice truly fits the 4MB XCD L2.)
// Same tile/LDS scheme as v4: 32d x 256s, packed-bf16, pitch 260, 16.3KB.
// ---------------------------------------------------------------------------
#define TP_D 32
#define TP_S 256
#define TP_P 260

__global__ __launch_bounds__(256) void transpose_to_bf16_v5_blocked(
    const float* __restrict__ W, __hip_bfloat16* __restrict__ WTb) {
  __shared__ uint32_t tile[16 * TP_P];  // 16.3KB
  const int s0 = blockIdx.x * TP_S;
  const int d0 = blockIdx.y * TP_D;     // multiple of 32
  const int tid = threadIdx.x;
  const int w = tid >> 6, l = tid & 63;

  // Phase A: wave w loads rows w*8 .. w*8+7 (4 row-pairs); 1KB wave-load/row.
#pragma unroll
  for (int ii = 0; ii < 4; ++ii) {
    const int r = w * 8 + ii * 2;
    const int rp = (w << 2) + ii;  // r>>1, in [0,16)
    const vfloat4 va = __builtin_nontemporal_load(
        reinterpret_cast<const vfloat4*>(&W[(size_t)(d0 + r) * D_SAE + s0 + l * 4]));
    const vfloat4 vb = __builtin_nontemporal_load(
        reinterpret_cast<const vfloat4*>(&W[(size_t)(d0 + r + 1) * D_SAE + s0 + l * 4]));
    uint32_t u[4];
    u[0] = pack2_bf16(va.x, vb.x);
    u[1] = pack2_bf16(va.y, vb.y);
    u[2] = pack2_bf16(va.z, vb.z);
    u[3] = pack2_bf16(va.w, vb.w);
    *reinterpret_cast<uint4*>(&tile[rp * TP_P + l * 4]) =
        *reinterpret_cast<uint4*>(u);
  }
  __syncthreads();

  // Phase B: lane a=l&3 picks d-chunk of 8, sub=l>>2 picks s.
  const int a = l & 3;
  const int sub = l >> 2;
  const int slice = d0 >> 6;
  const int dlo = (d0 & 32) + a * 8;  // d offset within the 64-wide slice
  __hip_bfloat16* base = WTb + (size_t)slice * D_SAE * 64;
#pragma unroll
  for (int i = 0; i < 4; ++i) {
    const int sl = w * 64 + i * 16 + sub;
    uint32_t u[4];
#pragma unroll
    for (int j = 0; j < 4; ++j) {
      const int rp = a * 4 + j;
      u[j] = tile[rp * TP_P + sl];
    }
    *reinterpret_cast<uint4*>(&base[(size_t)(s0 + sl) * 64 + dlo]) =
        *reinterpret_cast<uint4*>(u);
  }
}

// ---------------------------------------------------------------------------
// Transpose v4 (row-major output) — kept for the r1 fallback path only.
// ---------------------------------------------------------------------------
__global__ __launch_bounds__(256) void transpose_to_bf16_v4(
    const float* __restrict__ W, __hip_bfloat16* __restrict__ WT) {
  __shared__ uint32_t tile[16 * TP_P];
  const int s0 = blockIdx.x * TP_S;
  const int d0 = blockIdx.y * TP_D;
  const int tid = threadIdx.x;
  const int w = tid >> 6, l = tid & 63;
#pragma unroll
  for (int ii = 0; ii < 4; ++ii) {
    const int r = w * 8 + ii * 2;
    const int rp = (w << 2) + ii;
    const vfloat4 va = __builtin_nontemporal_load(
        reinterpret_cast<const vfloat4*>(&W[(size_t)(d0 + r) * D_SAE + s0 + l * 4]));
    const vfloat4 vb = __builtin_nontemporal_load(
        reinterpret_cast<const vfloat4*>(&W[(size_t)(d0 + r + 1) * D_SAE + s0 + l * 4]));
    uint32_t u[4];
    u[0] = pack2_bf16(va.x, vb.x);
    u[1] = pack2_bf16(va.y, vb.y);
    u[2] = pack2_bf16(va.z, vb.z);
    u[3] = pack2_bf16(va.w, vb.w);
    *reinterpret_cast<uint4*>(&tile[rp * TP_P + l * 4]) =
        *reinterpret_cast<uint4*>(u);
  }
  __syncthreads();
  const int a = l & 3;
  const int sub = l >> 2;
#pragma unroll
  for (int i = 0; i < 4; ++i) {
    const int sl = w * 64 + i * 16 + sub;
    uint32_t u[4];
#pragma unroll
    for (int j = 0; j < 4; ++j) {
      u[j] = tile[(a * 4 + j) * TP_P + sl];
    }
    *reinterpret_cast<uint4*>(&WT[(size_t)(s0 + sl) * D_IN + d0 + a * 8]) =
        *reinterpret_cast<uint4*>(u);
  }
}

// ---------------------------------------------------------------------------
// Decode v6: slice loop inside block (R3 structure) + BLOCKED WT gather.
// Grid = 8 XCDs x 128 rowchunks = 1024 blocks; 4 blk/CU needed, 6 fit.
// Gather = one aligned 128B line at slice_base + idx*128B; slice region is
// contiguous 4MB -> uniform L2 set usage -> slice L2-resident for real.
// ---------------------------------------------------------------------------
__global__ __launch_bounds__(256) void sae_decode_blk(
    const uint16_t* __restrict__ idx16, const float* __restrict__ v_clean,
    const __hip_bfloat16* __restrict__ WTb, const float* __restrict__ bias,
    float* __restrict__ out) {
  const int m = blockIdx.x & 7;            // XCD
  const int rowchunk = blockIdx.x >> 3;    // 0..n_rows/64-1
  const int r0 = rowchunk * 64;
  const int tid = threadIdx.x;
  const int w = tid >> 6, l = tid & 63;

  __shared__ __align__(16) uint16_t s_idx[64 * K_NNZ];  // 8KB
  __shared__ __align__(16) float    s_val[64 * K_NNZ];  // 16KB

  {  // stage 64 rows of (idx16, v_clean) once; nt (read-once stream)
    const vuint4*  gi = reinterpret_cast<const vuint4*>(&idx16[(size_t)r0 * K_NNZ]);
    const vfloat4* gv = reinterpret_cast<const vfloat4*>(&v_clean[(size_t)r0 * K_NNZ]);
#pragma unroll
    for (int i = 0; i < 2; ++i) {
      const int e = i * 256 + tid;
      reinterpret_cast<vuint4*>(s_idx)[e] = __builtin_nontemporal_load(&gi[e]);
    }
#pragma unroll
    for (int i = 0; i < 4; ++i) {
      const int e = i * 256 + tid;
      reinterpret_cast<vfloat4*>(s_val)[e] = __builtin_nontemporal_load(&gv[e]);
    }
  }
  __syncthreads();

  const int kg = l >> 3;                 // k-group 0..7
  const int c  = l & 7;                  // 16B chunk 0..7

  for (int s = 0; s < 4; ++s) {          // slices m, m+8, m+16, m+24
    const int slice = s * 8 + m;
    const int col0 = slice * 64;
    const __hip_bfloat16* wbase = WTb + (size_t)slice * D_SAE * 64 + c * 8;

#pragma unroll 2
    for (int i = 0; i < 16; ++i) {
      const int r = w + 4 * i;
      float acc[8] = {0.f, 0.f, 0.f, 0.f, 0.f, 0.f, 0.f, 0.f};
#pragma unroll
      for (int step = 0; step < 8; ++step) {
        const int k = step * 8 + kg;
        const int idx = (int)s_idx[r * K_NNZ + k];  // broadcast across c
        const float v = s_val[r * K_NNZ + k];
        const uint4 wv = *reinterpret_cast<const uint4*>(&wbase[(size_t)idx * 64]);
#pragma unroll
        for (int j = 0; j < 4; ++j) {
          const uint32_t u = (&wv.x)[j];
          const float lo = __uint_as_float(u << 16);
          const float hi = __uint_as_float(u & 0xffff0000u);
          acc[2 * j + 0] = fmaf(v, lo, acc[2 * j + 0]);
          acc[2 * j + 1] = fmaf(v, hi, acc[2 * j + 1]);
        }
      }
#pragma unroll
      for (int j = 0; j < 8; ++j) {
        acc[j] += __shfl_xor(acc[j], 8, 64);
        acc[j] += __shfl_xor(acc[j], 16, 64);
        acc[j] += __shfl_xor(acc[j], 32, 64);
      }
      if (kg == 0) {
        const int dbase = col0 + c * 8;
        const float4 b0 = *reinterpret_cast<const float4*>(&bias[dbase]);
        const float4 b1 = *reinterpret_cast<const float4*>(&bias[dbase + 4]);
        vfloat4 o0 = {acc[0] + b0.x, acc[1] + b0.y, acc[2] + b0.z, acc[3] + b0.w};
        vfloat4 o1 = {acc[4] + b1.x, acc[5] + b1.y, acc[6] + b1.z, acc[7] + b1.w};
        vfloat4* o = reinterpret_cast<vfloat4*>(&out[(size_t)(r0 + r) * D_IN + dbase]);
        __builtin_nontemporal_store(o0, &o[0]);
        __builtin_nontemporal_store(o1, &o[1]);
      }
    }
  }
}

// ---------------------------------------------------------------------------
// Fallback (ws fits WT+v_clean only): int32-staging variant, blocked WT.
// ---------------------------------------------------------------------------
__global__ __launch_bounds__(256) void sae_decode_blk_i32(
    const int* __restrict__ indices, const float* __restrict__ v_clean,
    const __hip_bfloat16* __restrict__ WTb, const float* __restrict__ bias,
    float* __restrict__ out) {
  const int m = blockIdx.x & 7;
  const int rowchunk = blockIdx.x >> 3;
  const int r0 = rowchunk * 64;
  const int tid = threadIdx.x;
  const int w = tid >> 6, l = tid & 63;

  __shared__ __align__(16) int   s_idx[64 * K_NNZ];
  __shared__ __align__(16) float s_val[64 * K_NNZ];

  {
    const vint4*   gi = reinterpret_cast<const vint4*>(&indices[(size_t)r0 * K_NNZ]);
    const vfloat4* gv = reinterpret_cast<const vfloat4*>(&v_clean[(size_t)r0 * K_NNZ]);
#pragma unroll
    for (int i = 0; i < 4; ++i) {
      const int e = i * 256 + tid;
      reinterpret_cast<vint4*>(s_idx)[e] = __builtin_nontemporal_load(&gi[e]);
      reinterpret_cast<vfloat4*>(s_val)[e] = __builtin_nontemporal_load(&gv[e]);
    }
  }
  __syncthreads();

  const int kg = l >> 3;
  const int c  = l & 7;

  for (int s = 0; s < 4; ++s) {
    const int slice = s * 8 + m;
    const int col0 = slice * 64;
    const __hip_bfloat16* wbase = WTb + (size_t)slice * D_SAE * 64 + c * 8;

    for (int i = 0; i < 16; ++i) {
      const int r = w + 4 * i;
      float acc[8] = {0.f, 0.f, 0.f, 0.f, 0.f, 0.f, 0.f, 0.f};
#pragma unroll
      for (int step = 0; step < 8; ++step) {
        const int k = step * 8 + kg;
        const int idx = s_idx[r * K_NNZ + k];
        const float v = s_val[r * K_NNZ + k];
        const uint4 wv = *reinterpret_cast<const uint4*>(&wbase[(size_t)idx * 64]);
#pragma unroll
        for (int j = 0; j < 4; ++j) {
          const uint32_t u = (&wv.x)[j];
          const float lo = __uint_as_float(u << 16);
          const float hi = __uint_as_float(u & 0xffff0000u);
          acc[2 * j + 0] = fmaf(v, lo, acc[2 * j + 0]);
          acc[2 * j + 1] = fmaf(v, hi, acc[2 * j + 1]);
        }
      }
#pragma unroll
      for (int j = 0; j < 8; ++j) {
        acc[j] += __shfl_xor(acc[j], 8, 64);
        acc[j] += __shfl_xor(acc[j], 16, 64);
        acc[j] += __shfl_xor(acc[j], 32, 64);
      }
      if (kg == 0) {
        const int dbase = col0 + c * 8;
        const float4 b0 = *reinterpret_cast<const float4*>(&bias[dbase]);
        const float4 b1 = *reinterpret_cast<const float4*>(&bias[dbase + 4]);
        vfloat4 o0 = {acc[0] + b0.x, acc[1] + b0.y, acc[2] + b0.z, acc[3] + b0.w};
        vfloat4 o1 = {acc[4] + b1.x, acc[5] + b1.y, acc[6] + b1.z, acc[7] + b1.w};
        vfloat4* o = reinterpret_cast<vfloat4*>(&out[(size_t)(r0 + r) * D_IN + dbase]);
        __builtin_nontemporal_store(o0, &o[0]);
        __builtin_nontemporal_store(o1, &o[1]);
      }
    }
  }
}

// ---------------------------------------------------------------------------
// Fallback A (ws fits WT only): R1's proven decode (row-major WT).
// ---------------------------------------------------------------------------
__global__ __launch_bounds__(256) void sae_decode_r1(
    const int* __restrict__ indices, const float* __restrict__ values,
    const __hip_bfloat16* __restrict__ WT, const float* __restrict__ bias,
    float* __restrict__ out) {
  const int row = blockIdx.x;
  const int tid = threadIdx.x;

  __shared__ int   s_idx[K_NNZ];
  __shared__ float s_val[K_NNZ];
  if (tid < K_NNZ) {
    s_idx[tid] = indices[(size_t)row * K_NNZ + tid];
    s_val[tid] = values[(size_t)row * K_NNZ + tid];
  }
  __syncthreads();
  if (tid < K_NNZ) {
    const int my = s_idx[tid];
    for (int k2 = tid + 1; k2 < K_NNZ; ++k2) {
      if (s_idx[k2] == my) { s_val[tid] = 0.0f; break; }
    }
  }
  __syncthreads();

  const int d0 = tid * 8;
  float acc[8];
  {
    const float4 b0 = *reinterpret_cast<const float4*>(&bias[d0]);
    const float4 b1 = *reinterpret_cast<const float4*>(&bias[d0 + 4]);
    acc[0] = b0.x; acc[1] = b0.y; acc[2] = b0.z; acc[3] = b0.w;
    acc[4] = b1.x; acc[5] = b1.y; acc[6] = b1.z; acc[7] = b1.w;
  }
#pragma unroll 4
  for (int k = 0; k < K_NNZ; ++k) {
    const float v = s_val[k];
    const int idx = s_idx[k];
    const uint4 wv = *reinterpret_cast<const uint4*>(
        &WT[(size_t)idx * D_IN + d0]);
#pragma unroll
    for (int j = 0; j < 4; ++j) {
      const uint32_t u = (&wv.x)[j];
      const float lo = __uint_as_float(u << 16);
      const float hi = __uint_as_float(u & 0xffff0000u);
      acc[2 * j + 0] = fmaf(v, lo, acc[2 * j + 0]);
      acc[2 * j + 1] = fmaf(v, hi, acc[2 * j + 1]);
    }
  }
  float4* o = reinterpret_cast<float4*>(&out[(size_t)row * D_IN + d0]);
  o[0] = make_float4(acc[0], acc[1], acc[2], acc[3]);
  o[1] = make_float4(acc[4], acc[5], acc[6], acc[7]);
}

// ---------------------------------------------------------------------------
// Fallback B (tiny ws): direct fp32 gather. Insurance only.
// ---------------------------------------------------------------------------
__global__ __launch_bounds__(256) void sae_decode_direct(
    const int* __restrict__ indices, const float* __restrict__ values,
    const float* __restrict__ W, const float* __restrict__ bias,
    float* __restrict__ out) {
  const int row = blockIdx.x;
  const int tid = threadIdx.x;
  __shared__ int   s_idx[K_NNZ];
  __shared__ float s_val[K_NNZ];
  if (tid < K_NNZ) {
    s_idx[tid] = indices[(size_t)row * K_NNZ + tid];
    s_val[tid] = values[(size_t)row * K_NNZ + tid];
  }
  __syncthreads();
  if (tid < K_NNZ) {
    const int my = s_idx[tid];
    for (int k2 = tid + 1; k2 < K_NNZ; ++k2) {
      if (s_idx[k2] == my) { s_val[tid] = 0.0f; break; }
    }
  }
  __syncthreads();
  const int d0 = tid * 8;
  float acc[8];
#pragma unroll
  for (int j = 0; j < 8; ++j) acc[j] = bias[d0 + j];
  for (int k = 0; k < K_NNZ; ++k) {
    const float v = s_val[k];
    const int idx = s_idx[k];
#pragma unroll
    for (int j = 0; j < 8; ++j) {
      acc[j] = fmaf(v, W[(size_t)(d0 + j) * D_SAE + idx], acc[j]);
    }
  }
  float4* o = reinterpret_cast<float4*>(&out[(size_t)row * D_IN + d0]);
  o[0] = make_float4(acc[0], acc[1], acc[2], acc[3]);
  o[1] = make_float4(acc[4], acc[5], acc[6], acc[7]);
}

extern "C" void kernel_launch(void* const* d_in, const int* in_sizes, int n_in,
                              void* d_out, int out_size, void* d_ws, size_t ws_size,
                              hipStream_t stream) {
  const int*   indices = (const int*)d_in[0];
  const float* values  = (const float*)d_in[1];
  const float* W       = (const float*)d_in[2];
  const float* bias    = (const float*)d_in[3];
  float* out = (float*)d_out;

  const int n_rows = in_sizes[0] / K_NNZ;  // 8192
  const size_t wt_bytes = (size_t)D_SAE * D_IN * sizeof(__hip_bfloat16);  // 128MB
  const size_t vc_bytes = (size_t)n_rows * K_NNZ * sizeof(float);         // 2MB
  const size_t ix_bytes = (size_t)n_rows * K_NNZ * sizeof(uint16_t);      // 1MB

  if (ws_size >= wt_bytes + vc_bytes + ix_bytes && (n_rows % 64) == 0) {
    __hip_bfloat16* WTb = (__hip_bfloat16*)d_ws;
    float* v_clean = (float*)((char*)d_ws + wt_bytes);
    uint16_t* idx16 = (uint16_t*)((char*)d_ws + wt_bytes + vc_bytes);
    transpose_to_bf16_v5_blocked<<<dim3(D_SAE / TP_S, D_IN / TP_D), 256, 0,
                                   stream>>>(W, WTb);
    dedup_values_v2<<<n_rows, 64, 0, stream>>>(indices, values, v_clean, idx16);
    sae_decode_blk<<<8 * (n_rows / 64), 256, 0, stream>>>(idx16, v_clean, WTb,
                                                          bias, out);
  } else if (ws_size >= wt_bytes + vc_bytes && (n_rows % 64) == 0) {
    __hip_bfloat16* WTb = (__hip_bfloat16*)d_ws;
    float* v_clean = (float*)((char*)d_ws + wt_bytes);
    transpose_to_bf16_v5_blocked<<<dim3(D_SAE / TP_S, D_IN / TP_D), 256, 0,
                                   stream>>>(W, WTb);
    dedup_values_v2<<<n_rows, 64, 0, stream>>>(indices, values, v_clean,
                                               (uint16_t*)nullptr);
    sae_decode_blk_i32<<<8 * (n_rows / 64), 256, 0, stream>>>(indices, v_clean,
                                                              WTb, bias, out);
  } else if (ws_size >= wt_bytes) {
    __hip_bfloat16* WT = (__hip_bfloat16*)d_ws;
    transpose_to_bf16_v4<<<dim3(D_SAE / TP_S, D_IN / TP_D), 256, 0, stream>>>(W, WT);
    sae_decode_r1<<<n_rows, 256, 0, stream>>>(indices, values, WT, bias, out);
  } else {
    sae_decode_direct<<<n_rows, 256, 0, stream>>>(indices, values, W, bias, out);
  }
}